// Round 7
// baseline (594.393 us; speedup 1.0000x reference)
//
#include <hip/hip_runtime.h>
#include <hip/hip_bf16.h>
#include <cstdint>

// Qwen3-VL-MoE text experts: permute -> grouped GEMM (gate_up) -> SwiGLU ->
// grouped GEMM (down) -> unpermute+combine.  bf16 MFMA path.
// R7: weight transpose passes ELIMINATED.  GEMMs reg-stage B from native f32
// layout (coalesced f32x4), convert f32->bf16 in-register, ds_write into a
// k-contiguous pitch-40 LDS tile (2-slot ring).  A keeps the proven
// gload_lds + XOR-swizzle 4-slot ring.  Counted vmcnt(6), never drained in
// steady state.  T1..T5 schedule otherwise identical to R6.

#define E_   32
#define H_   2048
#define D_   768
#define T_   4096
#define K_   8
#define M_   (T_ * K_)   // 32768 expanded rows
#define G_   (M_ / E_)   // 1024 rows per expert (balanced)
#define GU2  (2 * D_)    // 1536
#define BPITCH 40        // B LDS row pitch in u16 (80 B, 16B-aligned, bank-spread)

typedef unsigned short u16;
typedef short bf16x8 __attribute__((ext_vector_type(8)));
typedef float f32x4 __attribute__((ext_vector_type(4)));
typedef unsigned short u16x2 __attribute__((ext_vector_type(2)));
typedef unsigned short u16x4 __attribute__((ext_vector_type(4)));
typedef unsigned short u16x8 __attribute__((ext_vector_type(8)));

__device__ __forceinline__ u16 f2bf(float f) {          // RNE f32 -> bf16
  unsigned u = __float_as_uint(f);
  u += 0x7FFFu + ((u >> 16) & 1u);
  return (u16)(u >> 16);
}
__device__ __forceinline__ float bf2f(u16 v) {
  return __uint_as_float(((unsigned)v) << 16);
}

#define GLOAD16(g, l) __builtin_amdgcn_global_load_lds(                        \
    (const __attribute__((address_space(1))) void*)(g),                        \
    (__attribute__((address_space(3))) void*)(l), 16, 0, 0)

#define VM6()   asm volatile("s_waitcnt vmcnt(6)" ::: "memory")
#define VM0()   asm volatile("s_waitcnt vmcnt(0)" ::: "memory")
#define LGKM0() asm volatile("s_waitcnt lgkmcnt(0)" ::: "memory")
#define SCHB()  __builtin_amdgcn_sched_barrier(0)
#define BAR()   __builtin_amdgcn_s_barrier()

// ---------------------------------------------------------------- prep ------
__global__ __launch_bounds__(256) void cvt_hidden(const float* __restrict__ in,
                                                  u16* __restrict__ out) {
  const int i = blockIdx.x * 256 + threadIdx.x;       // float4 groups
  const float4 v = ((const float4*)in)[i];
  u16x2 a; a.x = f2bf(v.x); a.y = f2bf(v.y);
  u16x2 b; b.x = f2bf(v.z); b.y = f2bf(v.w);
  *(u16x2*)&out[(size_t)i * 4]     = a;
  *(u16x2*)&out[(size_t)i * 4 + 2] = b;
}

// ------------------------------------------------------------- routing -----
// Two-level atomic ranking: LDS histogram + one global atomicAdd per expert
// per block.  Order within an expert group is arbitrary; output values are
// independent of it (each row's dot products don't depend on its position).
__global__ __launch_bounds__(256) void build_perm_fast(const int* __restrict__ ridx,
                                                       int* __restrict__ perm,
                                                       int* __restrict__ gcnt) {
  __shared__ int lc[E_];
  __shared__ int lb[E_];
  const int tid = threadIdx.x;
  if (tid < E_) lc[tid] = 0;
  __syncthreads();
  const int i = blockIdx.x * 256 + tid;
  const int e = ridx[i];
  const int p = atomicAdd(&lc[e], 1);
  __syncthreads();
  if (tid < E_) lb[tid] = atomicAdd(&gcnt[tid], lc[tid]);
  __syncthreads();
  perm[e * G_ + lb[e] + p] = i;
}

// --------------------------------------------------------------- GEMM1 -----
// 256x256 tile, BK=32.  A: 4-slot gload_lds ring (XOR swizzle, as R6).
// B: native (E,H,1536) f32, reg-staged 2 tiles ahead, cvt->bf16, ds_write
// into 2-slot pitch-40 k-contiguous tile.  8 waves (2M x 4N), 128x64/wave.
__global__ __launch_bounds__(512, 2) void gemm1_swiglu(
    const u16* __restrict__ hid, const float* __restrict__ gup,
    const int* __restrict__ perm, u16* __restrict__ act) {
  __shared__ u16 As[4][8192];          // 4 x 16 KiB
  __shared__ u16 Bs[2][256 * BPITCH];  // 2 x 20 KiB  (total 104 KiB)
  const int NT = H_ / 32;              // 64 K-tiles

  const int nwg = 6 * 4 * E_;          // 768, %8==0
  const int wid = (blockIdx.x % 8) * (nwg / 8) + blockIdx.x / 8;
  const int e = wid / 24;
  const int mb = (wid / 6) % 4;
  const int nb = wid % 6;

  const int tid = threadIdx.x;
  const int lane = tid & 63, w = tid >> 6;
  const int wr = w >> 2, wc = w & 3;   // 2 x 4 wave grid

  // ---- A staging (unchanged from R6): row q*128 + tid>>2, chunk tid&3,
  // source pre-swizzled so aoff reads below are conflict-free.
  const int srow = tid >> 2, schunk = tid & 3;
  const u16* pA[2];
#pragma unroll
  for (int q = 0; q < 2; ++q) {
    const int r = q * 128 + srow;
    const int cg = (schunk ^ ((r >> 1) & 3)) * 8;
    const int token = perm[e * G_ + mb * 256 + r] >> 3;
    pA[q] = hid + (size_t)token * H_ + cg;
  }

  // ---- B staging map: thread covers 4 d-cols x 4 k-rows of the native tile.
  // hq = k-quad (0..7), d4 = d-quad (0..31), rt = gate/up half.
  const int rt = tid >> 8;             // 0 = gate, 1 = up
  const int u  = tid & 255;
  const int hq = u & 7;                // k-quad -> h0 = hq*4
  const int d4 = u >> 3;               // 0..31 -> dloc = d4*4
  const int dloc = d4 * 4;
  const int h0 = hq * 4;
  const int gc = rt * D_ + nb * 128 + dloc;                    // col in (..,1536)
  const int rb = (dloc >> 4) * 32 + rt * 16 + (dloc & 15);     // LDS row base
  const float* bsA = gup + ((size_t)e * H_ + h0) * GU2 + gc;   // + (t*32+j)*1536

  // ---- ds-read offsets: A swizzled (as R6); B pitch-40 linear.
  int aoff[8], boff[4];
  {
    const int l15 = lane & 15, hk = lane >> 4;
#pragma unroll
    for (int m = 0; m < 8; ++m) {
      const int rA = wr * 128 + m * 16 + l15;
      aoff[m] = rA * 32 + ((hk ^ ((rA >> 1) & 3)) * 8);
    }
#pragma unroll
    for (int n = 0; n < 4; ++n) {
      const int rB = wc * 64 + n * 16 + l15;
      boff[n] = rB * BPITCH + hk * 8;
    }
  }

  f32x4 acc[8][4];
#pragma unroll
  for (int m = 0; m < 8; ++m)
#pragma unroll
    for (int n = 0; n < 4; ++n) acc[m][n] = (f32x4){0.f, 0.f, 0.f, 0.f};

  // ---- prologue: A(0),B(0),A(1),B(1); process B(0); queue = [A1 x2, B1 x4]
  f32x4 Lcur[4], Lnxt[4];
  GLOAD16(pA[0], &As[0][tid * 8]);      GLOAD16(pA[1], &As[0][4096 + tid * 8]);
  SCHB();
#pragma unroll
  for (int j = 0; j < 4; ++j) Lcur[j] = *(const f32x4*)(bsA + (size_t)j * GU2);
  SCHB();
  GLOAD16(pA[0] + 32, &As[1][tid * 8]); GLOAD16(pA[1] + 32, &As[1][4096 + tid * 8]);
  SCHB();
#pragma unroll
  for (int j = 0; j < 4; ++j) Lnxt[j] = *(const f32x4*)(bsA + (size_t)(32 + j) * GU2);
  SCHB();
  VM6();                               // A(0), B(0) landed
#pragma unroll
  for (int i = 0; i < 4; ++i) {
    const int r = rb + i;
    u16x4 v;
    v[0] = f2bf(Lcur[0][i]); v[1] = f2bf(Lcur[1][i]);
    v[2] = f2bf(Lcur[2][i]); v[3] = f2bf(Lcur[3][i]);
    *(u16x4*)&Bs[0][r * BPITCH + h0] = v;
  }
#pragma unroll
  for (int j = 0; j < 4; ++j) Lcur[j] = Lnxt[j];
  LGKM0(); BAR(); SCHB();

#pragma unroll 2
  for (int t = 0; t < NT; ++t) {
    const int slot = t & 3, ts = (t + 2) & 3;
    const bool st2 = (t + 2) < NT, st1 = (t + 1) < NT;
    const u16* Ab = As[slot]; const u16* Bb = Bs[t & 1];
    bf16x8 av[4], bv[4];
    // ---- phase A: read b[0..3]+a[0..3]; issue A-gload(t+2); 16 MFMA
#pragma unroll
    for (int n = 0; n < 4; ++n) bv[n] = *(const bf16x8*)&Bb[boff[n]];
#pragma unroll
    for (int m = 0; m < 4; ++m) av[m] = *(const bf16x8*)&Ab[aoff[m]];
    if (st2) {
      GLOAD16(pA[0] + (t + 2) * 32, &As[ts][tid * 8]);
      GLOAD16(pA[1] + (t + 2) * 32, &As[ts][4096 + tid * 8]);
    }
    SCHB(); BAR(); LGKM0(); SCHB();
    __builtin_amdgcn_s_setprio(1);
#pragma unroll
    for (int m = 0; m < 4; ++m)
#pragma unroll
      for (int n = 0; n < 4; ++n)
        acc[m][n] = __builtin_amdgcn_mfma_f32_16x16x32_bf16(av[m], bv[n],
                                                            acc[m][n], 0, 0, 0);
    __builtin_amdgcn_s_setprio(0);
    SCHB(); BAR();
    // ---- phase B: read a[4..7]; issue B-f32-loads(t+2); 16 MFMA
#pragma unroll
    for (int m = 0; m < 4; ++m) av[m] = *(const bf16x8*)&Ab[aoff[m + 4]];
    f32x4 Lnew[4];
    if (st2) {
#pragma unroll
      for (int j = 0; j < 4; ++j)
        Lnew[j] = *(const f32x4*)(bsA + (size_t)((t + 2) * 32 + j) * GU2);
    }
    SCHB(); BAR(); LGKM0(); SCHB();
    __builtin_amdgcn_s_setprio(1);
#pragma unroll
    for (int m = 0; m < 4; ++m)
#pragma unroll
      for (int n = 0; n < 4; ++n)
        acc[m + 4][n] = __builtin_amdgcn_mfma_f32_16x16x32_bf16(av[m], bv[n],
                                                                acc[m + 4][n], 0, 0, 0);
    __builtin_amdgcn_s_setprio(0);
    SCHB();
    // ---- boundary: retire t+1's A(2)+B(4); write B(t+1); t+2 stays in flight
    if (st2)      { VM6(); }
    else if (st1) { VM0(); }
    if (st1) {
#pragma unroll
      for (int i = 0; i < 4; ++i) {
        const int r = rb + i;
        u16x4 v;
        v[0] = f2bf(Lcur[0][i]); v[1] = f2bf(Lcur[1][i]);
        v[2] = f2bf(Lcur[2][i]); v[3] = f2bf(Lcur[3][i]);
        *(u16x4*)&Bs[(t + 1) & 1][r * BPITCH + h0] = v;
      }
#pragma unroll
      for (int j = 0; j < 4; ++j) Lcur[j] = Lnew[j];
      LGKM0();
    }
    BAR(); SCHB();
  }

  // epilogue: SwiGLU on paired (gate,up) fragments, store bf16 act
  const int lrow = (lane >> 4) * 4, lcol = lane & 15;
#pragma unroll
  for (int m = 0; m < 8; ++m)
#pragma unroll
    for (int p = 0; p < 2; ++p)
#pragma unroll
      for (int r = 0; r < 4; ++r) {
        const float g = acc[m][2 * p][r];
        const float uu = acc[m][2 * p + 1][r];
        const float a_ = g / (1.f + __expf(-g)) * uu;    // silu(g)*u
        const int row = mb * 256 + wr * 128 + m * 16 + lrow + r;
        const int dcol = (nb * 8 + wc * 2 + p) * 16 + lcol;
        act[((size_t)e * G_ + row) * D_ + dcol] = f2bf(a_);
      }
}

// --------------------------------------------------------------- GEMM2 -----
// Same structure, K=768.  B: native (E,D,H) f32 reg-staged.  Epilogue
// scatters rows to expanded order.
__global__ __launch_bounds__(512, 2) void gemm2_scatter(
    const u16* __restrict__ act, const float* __restrict__ dwn,
    const int* __restrict__ perm, u16* __restrict__ expo) {
  __shared__ u16 As[4][8192];
  __shared__ u16 Bs[2][256 * BPITCH];
  const int NT = D_ / 32;              // 24 K-tiles

  const int nwg = 8 * 4 * E_;          // 1024, %8==0
  const int wid = (blockIdx.x % 8) * (nwg / 8) + blockIdx.x / 8;
  const int e = wid / 32;
  const int mb = (wid / 8) % 4;
  const int nb = wid % 8;

  const int tid = threadIdx.x;
  const int lane = tid & 63, w = tid >> 6;
  const int wr = w >> 2, wc = w & 3;

  const int srow = tid >> 2, schunk = tid & 3;
  const u16* pA[2];
#pragma unroll
  for (int q = 0; q < 2; ++q) {
    const int r = q * 128 + srow;
    const int cg = (schunk ^ ((r >> 1) & 3)) * 8;
    pA[q] = act + ((size_t)e * G_ + mb * 256 + r) * D_ + cg;
  }

  // B map: kq = k-quad (0..7) -> d0 = kq*4; h64 (0..63) -> 4 h-rows rb..rb+3.
  const int kq  = tid & 7;
  const int h64 = (tid >> 3) & 63;
  const int d0  = kq * 4;
  const int rb  = h64 * 4;
  const float* bsB = dwn + ((size_t)e * D_ + d0) * H_ + nb * 256 + rb;

  int aoff[8], boff[4];
  {
    const int l15 = lane & 15, hk = lane >> 4;
#pragma unroll
    for (int m = 0; m < 8; ++m) {
      const int rA = wr * 128 + m * 16 + l15;
      aoff[m] = rA * 32 + ((hk ^ ((rA >> 1) & 3)) * 8);
    }
#pragma unroll
    for (int n = 0; n < 4; ++n) {
      const int rB = wc * 64 + n * 16 + l15;
      boff[n] = rB * BPITCH + hk * 8;
    }
  }

  f32x4 acc[8][4];
#pragma unroll
  for (int m = 0; m < 8; ++m)
#pragma unroll
    for (int n = 0; n < 4; ++n) acc[m][n] = (f32x4){0.f, 0.f, 0.f, 0.f};

  f32x4 Lcur[4], Lnxt[4];
  GLOAD16(pA[0], &As[0][tid * 8]);      GLOAD16(pA[1], &As[0][4096 + tid * 8]);
  SCHB();
#pragma unroll
  for (int j = 0; j < 4; ++j) Lcur[j] = *(const f32x4*)(bsB + (size_t)j * H_);
  SCHB();
  GLOAD16(pA[0] + 32, &As[1][tid * 8]); GLOAD16(pA[1] + 32, &As[1][4096 + tid * 8]);
  SCHB();
#pragma unroll
  for (int j = 0; j < 4; ++j) Lnxt[j] = *(const f32x4*)(bsB + (size_t)(32 + j) * H_);
  SCHB();
  VM6();
#pragma unroll
  for (int i = 0; i < 4; ++i) {
    const int r = rb + i;
    u16x4 v;
    v[0] = f2bf(Lcur[0][i]); v[1] = f2bf(Lcur[1][i]);
    v[2] = f2bf(Lcur[2][i]); v[3] = f2bf(Lcur[3][i]);
    *(u16x4*)&Bs[0][r * BPITCH + d0] = v;
  }
#pragma unroll
  for (int j = 0; j < 4; ++j) Lcur[j] = Lnxt[j];
  LGKM0(); BAR(); SCHB();

#pragma unroll 2
  for (int t = 0; t < NT; ++t) {
    const int slot = t & 3, ts = (t + 2) & 3;
    const bool st2 = (t + 2) < NT, st1 = (t + 1) < NT;
    const u16* Ab = As[slot]; const u16* Bb = Bs[t & 1];
    bf16x8 av[4], bv[4];
#pragma unroll
    for (int n = 0; n < 4; ++n) bv[n] = *(const bf16x8*)&Bb[boff[n]];
#pragma unroll
    for (int m = 0; m < 4; ++m) av[m] = *(const bf16x8*)&Ab[aoff[m]];
    if (st2) {
      GLOAD16(pA[0] + (t + 2) * 32, &As[ts][tid * 8]);
      GLOAD16(pA[1] + (t + 2) * 32, &As[ts][4096 + tid * 8]);
    }
    SCHB(); BAR(); LGKM0(); SCHB();
    __builtin_amdgcn_s_setprio(1);
#pragma unroll
    for (int m = 0; m < 4; ++m)
#pragma unroll
      for (int n = 0; n < 4; ++n)
        acc[m][n] = __builtin_amdgcn_mfma_f32_16x16x32_bf16(av[m], bv[n],
                                                            acc[m][n], 0, 0, 0);
    __builtin_amdgcn_s_setprio(0);
    SCHB(); BAR();
#pragma unroll
    for (int m = 0; m < 4; ++m) av[m] = *(const bf16x8*)&Ab[aoff[m + 4]];
    f32x4 Lnew[4];
    if (st2) {
#pragma unroll
      for (int j = 0; j < 4; ++j)
        Lnew[j] = *(const f32x4*)(bsB + (size_t)((t + 2) * 32 + j) * H_);
    }
    SCHB(); BAR(); LGKM0(); SCHB();
    __builtin_amdgcn_s_setprio(1);
#pragma unroll
    for (int m = 0; m < 4; ++m)
#pragma unroll
      for (int n = 0; n < 4; ++n)
        acc[m + 4][n] = __builtin_amdgcn_mfma_f32_16x16x32_bf16(av[m], bv[n],
                                                                acc[m + 4][n], 0, 0, 0);
    __builtin_amdgcn_s_setprio(0);
    SCHB();
    if (st2)      { VM6(); }
    else if (st1) { VM0(); }
    if (st1) {
#pragma unroll
      for (int i = 0; i < 4; ++i) {
        const int r = rb + i;
        u16x4 v;
        v[0] = f2bf(Lcur[0][i]); v[1] = f2bf(Lcur[1][i]);
        v[2] = f2bf(Lcur[2][i]); v[3] = f2bf(Lcur[3][i]);
        *(u16x4*)&Bs[(t + 1) & 1][r * BPITCH + d0] = v;
      }
#pragma unroll
      for (int j = 0; j < 4; ++j) Lcur[j] = Lnew[j];
      LGKM0();
    }
    BAR(); SCHB();
  }

  const int lrow = (lane >> 4) * 4, lcol = lane & 15;
#pragma unroll
  for (int m = 0; m < 8; ++m)
#pragma unroll
    for (int r = 0; r < 4; ++r) {
      const int dst = e * G_ + mb * 256 + wr * 128 + m * 16 + lrow + r;
      const int src = perm[dst];                 // expanded index t*K+k
      u16* orow = expo + (size_t)src * H_ + nb * 256 + wc * 64;
#pragma unroll
      for (int n = 0; n < 4; ++n)
        orow[n * 16 + lcol] = f2bf(acc[m][n][r]);
    }
}

// ------------------------------------------------------------- combine -----
__global__ __launch_bounds__(256) void combine(const u16* __restrict__ expo,
                                               const int* __restrict__ ridx,
                                               const float* __restrict__ rw,
                                               float* __restrict__ out) {
  __shared__ float pr[K_];
  const int t = blockIdx.x;
  if (threadIdx.x < K_)
    pr[threadIdx.x] = rw[t * E_ + ridx[t * K_ + threadIdx.x]];
  __syncthreads();
  const int h0 = threadIdx.x * 8;
  float r[8] = {0.f, 0.f, 0.f, 0.f, 0.f, 0.f, 0.f, 0.f};
#pragma unroll
  for (int k = 0; k < K_; ++k) {
    const float p = pr[k];
    const u16x8 v = *(const u16x8*)&expo[((size_t)(t * K_ + k)) * H_ + h0];
#pragma unroll
    for (int j = 0; j < 8; ++j) r[j] += p * bf2f(v[j]);
  }
  float4 o0 = {r[0], r[1], r[2], r[3]};
  float4 o1 = {r[4], r[5], r[6], r[7]};
  *(float4*)&out[(size_t)t * H_ + h0]     = o0;
  *(float4*)&out[(size_t)t * H_ + h0 + 4] = o1;
}

// -------------------------------------------------------------- launch -----
extern "C" void kernel_launch(void* const* d_in, const int* in_sizes, int n_in,
                              void* d_out, int out_size, void* d_ws, size_t ws_size,
                              hipStream_t stream) {
  const float* hidden = (const float*)d_in[0];   // (T, H) f32
  const float* rw     = (const float*)d_in[1];   // (T, E) f32
  const int*   ridx   = (const int*)d_in[2];     // (T, K) i32
  const float* gup_f  = (const float*)d_in[3];   // (E, H, 2D) f32
  const float* dwn_f  = (const float*)d_in[4];   // (E, D, H) f32
  float* out = (float*)d_out;                    // (T, H) f32

  char* ws = (char*)d_ws;
  size_t off = 0;
  auto alloc = [&](size_t bytes) -> void* {
    void* p = ws + off;
    off += (bytes + 255) & ~(size_t)255;
    return p;
  };
  u16*   hid_bf = (u16*)alloc((size_t)T_ * H_ * 2);        //  16.8 MB
  u16*   act    = (u16*)alloc((size_t)M_ * D_ * 2);        //  50.3 MB
  u16*   expo   = (u16*)alloc((size_t)M_ * H_ * 2);        // 134.2 MB
  int*   perm   = (int*)alloc((size_t)M_ * 4);
  int*   gcnt   = (int*)alloc((size_t)E_ * 4);
  if (off > ws_size) return;   // workspace too small -> clean fail

  hipMemsetAsync(gcnt, 0, E_ * sizeof(int), stream);
  cvt_hidden<<<(T_ * H_ / 4) / 256, 256, 0, stream>>>(hidden, hid_bf);
  build_perm_fast<<<M_ / 256, 256, 0, stream>>>(ridx, perm, gcnt);
  gemm1_swiglu<<<6 * 4 * E_, 512, 0, stream>>>(hid_bf, gup_f, perm, act);
  gemm2_scatter<<<8 * 4 * E_, 512, 0, stream>>>(act, dwn_f, perm, expo);
  combine<<<T_, 256, 0, stream>>>(expo, ridx, rw, out);
}

// Round 8
// 528.655 us; speedup vs baseline: 1.1243x; 1.1243x over previous
//
#include <hip/hip_runtime.h>
#include <hip/hip_bf16.h>
#include <cstdint>

// Qwen3-VL-MoE text experts: permute -> grouped GEMM (gate_up) -> SwiGLU ->
// grouped GEMM (down) -> unpermute+combine.  bf16 MFMA path.
// R8: R6 base (pre-transposed bf16 weights, 4-slot depth-3 ring, counted
// vmcnt, T1/T2/T5) with the K-loop reduced to ONE barrier per K-tile:
// ds_reads and stage issues overlap MFMA execution; correctness from
// {per-wave lgkmcnt(0) for own ds_reads} + {VM8 + boundary barrier for
// cross-wave staging visibility} + {ring depth giving >=1 barrier of
// separation for WAR on slot (t+3)&3}.

#define E_   32
#define H_   2048
#define D_   768
#define T_   4096
#define K_   8
#define M_   (T_ * K_)   // 32768 expanded rows
#define G_   (M_ / E_)   // 1024 rows per expert (balanced)
#define GU2  (2 * D_)    // 1536

typedef unsigned short u16;
typedef short bf16x8 __attribute__((ext_vector_type(8)));
typedef float f32x4 __attribute__((ext_vector_type(4)));
typedef unsigned short u16x2 __attribute__((ext_vector_type(2)));
typedef unsigned short u16x8 __attribute__((ext_vector_type(8)));

__device__ __forceinline__ u16 f2bf(float f) {          // RNE f32 -> bf16
  unsigned u = __float_as_uint(f);
  u += 0x7FFFu + ((u >> 16) & 1u);
  return (u16)(u >> 16);
}
__device__ __forceinline__ float bf2f(u16 v) {
  return __uint_as_float(((unsigned)v) << 16);
}

#define GLOAD16(g, l) __builtin_amdgcn_global_load_lds(                        \
    (const __attribute__((address_space(1))) void*)(g),                        \
    (__attribute__((address_space(3))) void*)(l), 16, 0, 0)

#define VM8()   asm volatile("s_waitcnt vmcnt(8)" ::: "memory")
#define VM4()   asm volatile("s_waitcnt vmcnt(4)" ::: "memory")
#define VM0()   asm volatile("s_waitcnt vmcnt(0)" ::: "memory")
#define LGKM0() asm volatile("s_waitcnt lgkmcnt(0)" ::: "memory")
#define SCHB()  __builtin_amdgcn_sched_barrier(0)
#define BAR()   __builtin_amdgcn_s_barrier()

// ---------------------------------------------------------------- prep ------
__global__ __launch_bounds__(256) void cvt_hidden(const float* __restrict__ in,
                                                  u16* __restrict__ out) {
  const int i = blockIdx.x * 256 + threadIdx.x;       // float4 groups
  const float4 v = ((const float4*)in)[i];
  u16x2 a; a.x = f2bf(v.x); a.y = f2bf(v.y);
  u16x2 b; b.x = f2bf(v.z); b.y = f2bf(v.w);
  *(u16x2*)&out[(size_t)i * 4]     = a;
  *(u16x2*)&out[(size_t)i * 4 + 2] = b;
}

// in: (B, R, C) f32  ->  out: (B, C, R) bf16, with optional gate/up
// 16-column interleave remap of the output row (mode 1: C==1536,
// gate j -> (j>>4)*32 + (j&15), up j -> (j>>4)*32 + 16 + (j&15)).
// Col-major LDS tile (pitch 72): f32x4 reads, b128 LDS reads, 16B stores.
__global__ __launch_bounds__(256) void transpose_cvt(const float* __restrict__ in,
                                                     u16* __restrict__ out,
                                                     int R, int C, int mode) {
  __shared__ u16 tl[64 * 72];        // tl[c*72 + r]
  const int b = blockIdx.z;
  const int c0 = blockIdx.x * 64, r0 = blockIdx.y * 64;
  const int tid = threadIdx.x;
  const float* ip = in + ((size_t)b * R + r0) * C + c0;
  const int rr4 = tid >> 4;          // 0..15
  const int cc4 = (tid & 15) * 4;    // 0,4,..,60
#pragma unroll
  for (int p = 0; p < 4; ++p) {
    const int r = p * 16 + rr4;
    const float4 v = *(const float4*)&ip[(size_t)r * C + cc4];
    tl[(cc4 + 0) * 72 + r] = f2bf(v.x);
    tl[(cc4 + 1) * 72 + r] = f2bf(v.y);
    tl[(cc4 + 2) * 72 + r] = f2bf(v.z);
    tl[(cc4 + 3) * 72 + r] = f2bf(v.w);
  }
  __syncthreads();
  const int rs = (tid & 7) * 8;      // 8-row strip start
#pragma unroll
  for (int q = 0; q < 2; ++q) {
    const int c = q * 32 + (tid >> 3);
    const int gc = c0 + c;
    int rr;
    if (mode == 1) {
      const int j = (gc < D_) ? gc : (gc - D_);
      rr = (j >> 4) * 32 + ((gc < D_) ? 0 : 16) + (j & 15);
    } else {
      rr = gc;
    }
    const u16x8 v = *(const u16x8*)&tl[c * 72 + rs];
    *(u16x8*)&out[((size_t)b * C + rr) * R + r0 + rs] = v;
  }
}

// ------------------------------------------------------------- routing -----
// Two-level atomic ranking: LDS histogram + one global atomicAdd per expert
// per block.  Order within an expert group is arbitrary; output values are
// independent of it (each row's dot products don't depend on its position).
__global__ __launch_bounds__(256) void build_perm_fast(const int* __restrict__ ridx,
                                                       int* __restrict__ perm,
                                                       int* __restrict__ gcnt) {
  __shared__ int lc[E_];
  __shared__ int lb[E_];
  const int tid = threadIdx.x;
  if (tid < E_) lc[tid] = 0;
  __syncthreads();
  const int i = blockIdx.x * 256 + tid;
  const int e = ridx[i];
  const int p = atomicAdd(&lc[e], 1);
  __syncthreads();
  if (tid < E_) lb[tid] = atomicAdd(&gcnt[tid], lc[tid]);
  __syncthreads();
  perm[e * G_ + lb[e] + p] = i;
}

// --------------------------------------------------------------- GEMM1 -----
// 256x256 tile, BK=32, 4-slot ring, depth-3 prefetch, 8 waves (2M x 4N).
// ONE barrier per K-tile (boundary only).
__global__ __launch_bounds__(512, 2) void gemm1_swiglu(
    const u16* __restrict__ hid, const u16* __restrict__ gup,
    const int* __restrict__ perm, u16* __restrict__ act) {
  __shared__ u16 As[4][8192];   // 4 x 16 KiB
  __shared__ u16 Bs[4][8192];   // 4 x 16 KiB  (total 128 KiB)
  const int NT = H_ / 32;       // 64 K-tiles

  const int nwg = 6 * 4 * E_;   // 768, %8==0
  const int wid = (blockIdx.x % 8) * (nwg / 8) + blockIdx.x / 8;
  const int e = wid / 24;
  const int mb = (wid / 6) % 4;
  const int nb = wid % 6;

  const int tid = threadIdx.x;
  const int lane = tid & 63, w = tid >> 6;
  const int wr = w >> 2, wc = w & 3;           // 2 x 4 wave grid

  // staging sources: thread covers row (q*128 + tid>>2), 16B chunk (tid&3);
  // chunk pre-swizzled so ds_reads below are conflict-free (T2, rule #21).
  const int srow = tid >> 2, schunk = tid & 3;
  const u16* pA[2]; const u16* pB[2];
#pragma unroll
  for (int q = 0; q < 2; ++q) {
    const int r = q * 128 + srow;
    const int cg = (schunk ^ ((r >> 1) & 3)) * 8;
    const int token = perm[e * G_ + mb * 256 + r] >> 3;
    pA[q] = hid + (size_t)token * H_ + cg;
    pB[q] = gup + ((size_t)e * GU2 + nb * 256 + r) * H_ + cg;
  }

  // ds-read offsets (u16 units), swizzle matches staging pre-swizzle
  int aoff[8], boff[4];
  {
    const int l15 = lane & 15, hk = lane >> 4;
#pragma unroll
    for (int m = 0; m < 8; ++m) {
      const int rA = wr * 128 + m * 16 + l15;
      aoff[m] = rA * 32 + ((hk ^ ((rA >> 1) & 3)) * 8);
    }
#pragma unroll
    for (int n = 0; n < 4; ++n) {
      const int rB = wc * 64 + n * 16 + l15;
      boff[n] = rB * 32 + ((hk ^ ((rB >> 1) & 3)) * 8);
    }
  }

  f32x4 acc[8][4];
#pragma unroll
  for (int m = 0; m < 8; ++m)
#pragma unroll
    for (int n = 0; n < 4; ++n) acc[m][n] = (f32x4){0.f, 0.f, 0.f, 0.f};

  // prologue: stage tiles 0,1,2 into slots 0,1,2 (issue order = tile order)
  GLOAD16(pA[0], &As[0][tid * 8]);      GLOAD16(pA[1], &As[0][4096 + tid * 8]);
  GLOAD16(pB[0], &Bs[0][tid * 8]);      GLOAD16(pB[1], &Bs[0][4096 + tid * 8]);
  GLOAD16(pA[0] + 32, &As[1][tid * 8]); GLOAD16(pA[1] + 32, &As[1][4096 + tid * 8]);
  GLOAD16(pB[0] + 32, &Bs[1][tid * 8]); GLOAD16(pB[1] + 32, &Bs[1][4096 + tid * 8]);
  GLOAD16(pA[0] + 64, &As[2][tid * 8]); GLOAD16(pA[1] + 64, &As[2][4096 + tid * 8]);
  GLOAD16(pB[0] + 64, &Bs[2][tid * 8]); GLOAD16(pB[1] + 64, &Bs[2][4096 + tid * 8]);
  VM8(); BAR(); SCHB();                 // tile 0 landed; tiles 1,2 in flight

#pragma unroll 4
  for (int t = 0; t < NT; ++t) {
    const int slot = t & 3, ts = (t + 3) & 3;
    const bool st = (t + 3) < NT;
    const u16* Ab = As[slot]; const u16* Bb = Bs[slot];
    bf16x8 av[4], bv[4];
    // ---- phase A: read b[0..3]+a[0..3], stage A(t+3), 16 MFMA (no barrier)
#pragma unroll
    for (int n = 0; n < 4; ++n) bv[n] = *(const bf16x8*)&Bb[boff[n]];
#pragma unroll
    for (int m = 0; m < 4; ++m) av[m] = *(const bf16x8*)&Ab[aoff[m]];
    if (st) {
      GLOAD16(pA[0] + (t + 3) * 32, &As[ts][tid * 8]);
      GLOAD16(pA[1] + (t + 3) * 32, &As[ts][4096 + tid * 8]);
    }
    SCHB(); LGKM0(); SCHB();
    __builtin_amdgcn_s_setprio(1);
#pragma unroll
    for (int m = 0; m < 4; ++m)
#pragma unroll
      for (int n = 0; n < 4; ++n)
        acc[m][n] = __builtin_amdgcn_mfma_f32_16x16x32_bf16(av[m], bv[n],
                                                            acc[m][n], 0, 0, 0);
    __builtin_amdgcn_s_setprio(0);
    SCHB();
    // ---- phase B: read a[4..7], stage B(t+3), 16 MFMA (no barrier)
#pragma unroll
    for (int m = 0; m < 4; ++m) av[m] = *(const bf16x8*)&Ab[aoff[m + 4]];
    if (st) {
      GLOAD16(pB[0] + (t + 3) * 32, &Bs[ts][tid * 8]);
      GLOAD16(pB[1] + (t + 3) * 32, &Bs[ts][4096 + tid * 8]);
    }
    SCHB(); LGKM0(); SCHB();
    __builtin_amdgcn_s_setprio(1);
#pragma unroll
    for (int m = 0; m < 4; ++m)
#pragma unroll
      for (int n = 0; n < 4; ++n)
        acc[m + 4][n] = __builtin_amdgcn_mfma_f32_16x16x32_bf16(av[m], bv[n],
                                                                acc[m + 4][n], 0, 0, 0);
    __builtin_amdgcn_s_setprio(0);
    SCHB();
    // ---- boundary (the ONLY barrier): tile t+1 landed for every wave
    if (t + 3 < NT)      { VM8(); }
    else if (t + 2 < NT) { VM4(); }
    else                 { VM0(); }
    BAR(); SCHB();
  }

  // epilogue: SwiGLU on paired (gate,up) fragments, store bf16 act
  const int lrow = (lane >> 4) * 4, lcol = lane & 15;
#pragma unroll
  for (int m = 0; m < 8; ++m)
#pragma unroll
    for (int p = 0; p < 2; ++p)
#pragma unroll
      for (int r = 0; r < 4; ++r) {
        const float g = acc[m][2 * p][r];
        const float u = acc[m][2 * p + 1][r];
        const float a_ = g / (1.f + __expf(-g)) * u;     // silu(g)*u
        const int row = mb * 256 + wr * 128 + m * 16 + lrow + r;
        const int dcol = (nb * 8 + wc * 2 + p) * 16 + lcol;
        act[((size_t)e * G_ + row) * D_ + dcol] = f2bf(a_);
      }
}

// --------------------------------------------------------------- GEMM2 -----
// Same structure, K=768; one barrier per K-tile; scatter epilogue.
__global__ __launch_bounds__(512, 2) void gemm2_scatter(
    const u16* __restrict__ act, const u16* __restrict__ dwn,
    const int* __restrict__ perm, u16* __restrict__ expo) {
  __shared__ u16 As[4][8192];
  __shared__ u16 Bs[4][8192];
  const int NT = D_ / 32;       // 24 K-tiles

  const int nwg = 8 * 4 * E_;   // 1024, %8==0
  const int wid = (blockIdx.x % 8) * (nwg / 8) + blockIdx.x / 8;
  const int e = wid / 32;
  const int mb = (wid / 8) % 4;
  const int nb = wid % 8;

  const int tid = threadIdx.x;
  const int lane = tid & 63, w = tid >> 6;
  const int wr = w >> 2, wc = w & 3;

  const int srow = tid >> 2, schunk = tid & 3;
  const u16* pA[2]; const u16* pB[2];
#pragma unroll
  for (int q = 0; q < 2; ++q) {
    const int r = q * 128 + srow;
    const int cg = (schunk ^ ((r >> 1) & 3)) * 8;
    pA[q] = act + ((size_t)e * G_ + mb * 256 + r) * D_ + cg;
    pB[q] = dwn + ((size_t)e * H_ + nb * 256 + r) * D_ + cg;
  }

  int aoff[8], boff[4];
  {
    const int l15 = lane & 15, hk = lane >> 4;
#pragma unroll
    for (int m = 0; m < 8; ++m) {
      const int rA = wr * 128 + m * 16 + l15;
      aoff[m] = rA * 32 + ((hk ^ ((rA >> 1) & 3)) * 8);
    }
#pragma unroll
    for (int n = 0; n < 4; ++n) {
      const int rB = wc * 64 + n * 16 + l15;
      boff[n] = rB * 32 + ((hk ^ ((rB >> 1) & 3)) * 8);
    }
  }

  f32x4 acc[8][4];
#pragma unroll
  for (int m = 0; m < 8; ++m)
#pragma unroll
    for (int n = 0; n < 4; ++n) acc[m][n] = (f32x4){0.f, 0.f, 0.f, 0.f};

  GLOAD16(pA[0], &As[0][tid * 8]);      GLOAD16(pA[1], &As[0][4096 + tid * 8]);
  GLOAD16(pB[0], &Bs[0][tid * 8]);      GLOAD16(pB[1], &Bs[0][4096 + tid * 8]);
  GLOAD16(pA[0] + 32, &As[1][tid * 8]); GLOAD16(pA[1] + 32, &As[1][4096 + tid * 8]);
  GLOAD16(pB[0] + 32, &Bs[1][tid * 8]); GLOAD16(pB[1] + 32, &Bs[1][4096 + tid * 8]);
  GLOAD16(pA[0] + 64, &As[2][tid * 8]); GLOAD16(pA[1] + 64, &As[2][4096 + tid * 8]);
  GLOAD16(pB[0] + 64, &Bs[2][tid * 8]); GLOAD16(pB[1] + 64, &Bs[2][4096 + tid * 8]);
  VM8(); BAR(); SCHB();

#pragma unroll 4
  for (int t = 0; t < NT; ++t) {
    const int slot = t & 3, ts = (t + 3) & 3;
    const bool st = (t + 3) < NT;
    const u16* Ab = As[slot]; const u16* Bb = Bs[slot];
    bf16x8 av[4], bv[4];
#pragma unroll
    for (int n = 0; n < 4; ++n) bv[n] = *(const bf16x8*)&Bb[boff[n]];
#pragma unroll
    for (int m = 0; m < 4; ++m) av[m] = *(const bf16x8*)&Ab[aoff[m]];
    if (st) {
      GLOAD16(pA[0] + (t + 3) * 32, &As[ts][tid * 8]);
      GLOAD16(pA[1] + (t + 3) * 32, &As[ts][4096 + tid * 8]);
    }
    SCHB(); LGKM0(); SCHB();
    __builtin_amdgcn_s_setprio(1);
#pragma unroll
    for (int m = 0; m < 4; ++m)
#pragma unroll
      for (int n = 0; n < 4; ++n)
        acc[m][n] = __builtin_amdgcn_mfma_f32_16x16x32_bf16(av[m], bv[n],
                                                            acc[m][n], 0, 0, 0);
    __builtin_amdgcn_s_setprio(0);
    SCHB();
#pragma unroll
    for (int m = 0; m < 4; ++m) av[m] = *(const bf16x8*)&Ab[aoff[m + 4]];
    if (st) {
      GLOAD16(pB[0] + (t + 3) * 32, &Bs[ts][tid * 8]);
      GLOAD16(pB[1] + (t + 3) * 32, &Bs[ts][4096 + tid * 8]);
    }
    SCHB(); LGKM0(); SCHB();
    __builtin_amdgcn_s_setprio(1);
#pragma unroll
    for (int m = 0; m < 4; ++m)
#pragma unroll
      for (int n = 0; n < 4; ++n)
        acc[m + 4][n] = __builtin_amdgcn_mfma_f32_16x16x32_bf16(av[m], bv[n],
                                                                acc[m + 4][n], 0, 0, 0);
    __builtin_amdgcn_s_setprio(0);
    SCHB();
    if (t + 3 < NT)      { VM8(); }
    else if (t + 2 < NT) { VM4(); }
    else                 { VM0(); }
    BAR(); SCHB();
  }

  const int lrow = (lane >> 4) * 4, lcol = lane & 15;
#pragma unroll
  for (int m = 0; m < 8; ++m)
#pragma unroll
    for (int r = 0; r < 4; ++r) {
      const int dst = e * G_ + mb * 256 + wr * 128 + m * 16 + lrow + r;
      const int src = perm[dst];                 // expanded index t*K+k
      u16* orow = expo + (size_t)src * H_ + nb * 256 + wc * 64;
#pragma unroll
      for (int n = 0; n < 4; ++n)
        orow[n * 16 + lcol] = f2bf(acc[m][n][r]);
    }
}

// ------------------------------------------------------------- combine -----
__global__ __launch_bounds__(256) void combine(const u16* __restrict__ expo,
                                               const int* __restrict__ ridx,
                                               const float* __restrict__ rw,
                                               float* __restrict__ out) {
  __shared__ float pr[K_];
  const int t = blockIdx.x;
  if (threadIdx.x < K_)
    pr[threadIdx.x] = rw[t * E_ + ridx[t * K_ + threadIdx.x]];
  __syncthreads();
  const int h0 = threadIdx.x * 8;
  float r[8] = {0.f, 0.f, 0.f, 0.f, 0.f, 0.f, 0.f, 0.f};
#pragma unroll
  for (int k = 0; k < K_; ++k) {
    const float p = pr[k];
    const u16x8 v = *(const u16x8*)&expo[((size_t)(t * K_ + k)) * H_ + h0];
#pragma unroll
    for (int j = 0; j < 8; ++j) r[j] += p * bf2f(v[j]);
  }
  float4 o0 = {r[0], r[1], r[2], r[3]};
  float4 o1 = {r[4], r[5], r[6], r[7]};
  *(float4*)&out[(size_t)t * H_ + h0]     = o0;
  *(float4*)&out[(size_t)t * H_ + h0 + 4] = o1;
}

// -------------------------------------------------------------- launch -----
extern "C" void kernel_launch(void* const* d_in, const int* in_sizes, int n_in,
                              void* d_out, int out_size, void* d_ws, size_t ws_size,
                              hipStream_t stream) {
  const float* hidden = (const float*)d_in[0];   // (T, H) f32
  const float* rw     = (const float*)d_in[1];   // (T, E) f32
  const int*   ridx   = (const int*)d_in[2];     // (T, K) i32
  const float* gup_f  = (const float*)d_in[3];   // (E, H, 2D) f32
  const float* dwn_f  = (const float*)d_in[4];   // (E, D, H) f32
  float* out = (float*)d_out;                    // (T, H) f32

  char* ws = (char*)d_ws;
  size_t off = 0;
  auto alloc = [&](size_t bytes) -> void* {
    void* p = ws + off;
    off += (bytes + 255) & ~(size_t)255;
    return p;
  };
  u16*   hid_bf = (u16*)alloc((size_t)T_ * H_ * 2);        //  16.8 MB
  u16*   gup_t  = (u16*)alloc((size_t)E_ * GU2 * H_ * 2);  // 201.3 MB (E,1536i,H)
  u16*   dwn_t  = (u16*)alloc((size_t)E_ * H_ * D_ * 2);   // 100.7 MB (E,H,D)
  u16*   act    = (u16*)alloc((size_t)M_ * D_ * 2);        //  50.3 MB
  u16*   expo   = (u16*)alloc((size_t)M_ * H_ * 2);        // 134.2 MB
  int*   perm   = (int*)alloc((size_t)M_ * 4);
  int*   gcnt   = (int*)alloc((size_t)E_ * 4);
  if (off > ws_size) return;   // workspace too small -> clean fail

  hipMemsetAsync(gcnt, 0, E_ * sizeof(int), stream);
  cvt_hidden<<<(T_ * H_ / 4) / 256, 256, 0, stream>>>(hidden, hid_bf);
  transpose_cvt<<<dim3(GU2 / 64, H_ / 64, E_), 256, 0, stream>>>(gup_f, gup_t, H_, GU2, 1);
  transpose_cvt<<<dim3(H_ / 64, D_ / 64, E_), 256, 0, stream>>>(dwn_f, dwn_t, D_, H_, 0);
  build_perm_fast<<<M_ / 256, 256, 0, stream>>>(ridx, perm, gcnt);
  gemm1_swiglu<<<6 * 4 * E_, 512, 0, stream>>>(hid_bf, gup_t, perm, act);
  gemm2_scatter<<<8 * 4 * E_, 512, 0, stream>>>(act, dwn_t, perm, expo);
  combine<<<T_, 256, 0, stream>>>(expo, ridx, rw, out);
}